// Round 7
// baseline (205.225 us; speedup 1.0000x reference)
//
#include <hip/hip_runtime.h>

// RoIAlign forward, Detectron-style, sampling_ratio = 2.
// features: [N=2, C=256, H=200, W=200] fp32 ; rois: [1000,5] ; out: [1000,256,7,7]
//
// R7: transpose restructured for latency hiding. R6 was latency-bound (24%
// occupancy, VALUBusy 7%, 1.76 TB/s): per-iteration load->LDS-write deps kept
// only ~2 loads in flight, and 32 KB LDS capped resident blocks. New tile =
// 32ch x 200sp (one feature row): LDS 13 KB -> 8 blocks/CU (wave cap), grid
// 3200, and the fill phase loads ALL its float4s into registers before any
// LDS write (single vmcnt drain, ~7 loads in flight/thread). CT=32 keeps
// NHWC writes as full 64 B lines. Main kernel unchanged (R6-verified).

#define POOLED_H 7
#define POOLED_W 7
#define SPATIAL_SCALE 0.0625f
#define FEAT_N 2
#define FEAT_C 256
#define FEAT_H 200
#define FEAT_W 200
#define FEAT_S (FEAT_H * FEAT_W)               // 40000
#define IMG_USH ((size_t)FEAT_S * FEAT_C)      // ushorts per image in NHWC

// transpose tile: 32 channels x 200 spatial (one feature-map row)
#define ST 200            // spatial floats per tile (40000/200 = 200 exact)
#define ST4 (ST / 4)      // 50 float4 per channel row
#define CT 32             // channels per tile: 32 bf16 = one full 64 B line
#define SROW 204          // LDS row stride (ushorts); 204*2=408 B, 8-aligned
#define NF4 (CT * ST4)    // 1600 float4 per block
#define NRD (ST * 4)      // 800 uint4 readouts per block

__device__ __forceinline__ unsigned short f2bf(float f) {
    unsigned int u = __float_as_uint(f);
    u += 0x7fffu + ((u >> 16) & 1u);   // round-to-nearest-even
    return (unsigned short)(u >> 16);
}

// ---------- NCHW fp32 -> NHWC bf16 ----------
__global__ __launch_bounds__(256) void nchw_to_nhwc_bf16(
        const float* __restrict__ in, unsigned short* __restrict__ outp) {
    __shared__ unsigned short lds[CT * SROW];   // 13056 B -> 8 blocks/CU (wave cap)
    const int s0 = blockIdx.x * ST;
    const int c0 = blockIdx.y * CT;
    const int b = blockIdx.z;
    const int tid = threadIdx.x;

    // ---- fill: load ALL float4s into registers first (max MLP), then write ----
    const float* ibase = in + ((size_t)(b * FEAT_C + c0)) * FEAT_S + s0;
    float4 v[7];
    int fc[7], fj[7];
    int n = 0;
#pragma unroll
    for (int k = 0; k < 7; ++k) {
        int f = tid + 256 * k;
        if (f < NF4) {
            int c = f / ST4;           // const divisor -> magic mul
            int j = f - c * ST4;
            v[n] = *(const float4*)(ibase + (size_t)c * FEAT_S + 4 * j);
            fc[n] = c;
            fj[n] = j;
            ++n;
        }
    }
#pragma unroll
    for (int k = 0; k < 7; ++k) {
        if (k < n) {
            unsigned int p0 = (unsigned)f2bf(v[k].x) | ((unsigned)f2bf(v[k].y) << 16);
            unsigned int p1 = (unsigned)f2bf(v[k].z) | ((unsigned)f2bf(v[k].w) << 16);
            *(uint2*)(&lds[fc[k] * SROW + 4 * fj[k]]) = make_uint2(p0, p1);
        }
    }
    __syncthreads();

    // ---- readout: per spatial s, 32 ch x 2 B = one full 64 B line (4 uint4) ----
    unsigned short* obase = outp + ((size_t)b * FEAT_S + s0) * FEAT_C + c0;
#pragma unroll
    for (int k = 0; k < 4; ++k) {
        int f = tid + 256 * k;
        if (f < NRD) {
            int s = f >> 2;
            int m = f & 3;             // uint4 index: channels 8m..8m+7
            const unsigned short* lp = &lds[(8 * m) * SROW + s];
            unsigned int w0 = (unsigned)lp[0] | ((unsigned)lp[SROW] << 16);
            unsigned int w1 = (unsigned)lp[2 * SROW] | ((unsigned)lp[3 * SROW] << 16);
            unsigned int w2 = (unsigned)lp[4 * SROW] | ((unsigned)lp[5 * SROW] << 16);
            unsigned int w3 = (unsigned)lp[6 * SROW] | ((unsigned)lp[7 * SROW] << 16);
            *(uint4*)(obase + (size_t)s * FEAT_C + 8 * m) = make_uint4(w0, w1, w2, w3);
        }
    }
}

// ---------- main: block = (roi, 64-channel quarter) ----------
__global__ __launch_bounds__(256) void roialign_main(
        const unsigned short* __restrict__ feat,   // [N,H,W,C] bf16
        const float* __restrict__ rois,
        float* __restrict__ out,
        int num_rois) {
    __shared__ float outbuf[64 * 49];              // 12544 B
    __shared__ int s_ylo[14], s_yhi[14], s_xlo[14], s_xhi[14];
    __shared__ float s_ywl[14], s_ywh[14], s_xwl[14], s_xwh[14];

    const int bid = blockIdx.x;
    const int roi = bid >> 2;
    const int qc = (bid & 3) * 64;                 // channel quarter base

    const float* r = rois + roi * 5;
    const int b = (int)r[0];
    const float x1 = r[1] * SPATIAL_SCALE;
    const float y1 = r[2] * SPATIAL_SCALE;
    const float x2 = r[3] * SPATIAL_SCALE;
    const float y2 = r[4] * SPATIAL_SCALE;
    const float bin_w = fmaxf(x2 - x1, 1.0f) * (1.0f / POOLED_W);
    const float bin_h = fmaxf(y2 - y1, 1.0f) * (1.0f / POOLED_H);

    const int tid = threadIdx.x;
    if (tid < 14) {
        int p = tid >> 1, i = tid & 1;
        float yy = y1 + (float)p * bin_h + ((float)i + 0.5f) * bin_h * 0.5f;
        bool v = (yy > -1.0f) && (yy < (float)FEAT_H);
        float y = fmaxf(yy, 0.0f);
        int lo = min((int)floorf(y), FEAT_H - 1);
        int hi = min(lo + 1, FEAT_H - 1);
        if (lo >= FEAT_H - 1) y = (float)lo;       // edge snap (reference-exact)
        float l = y - (float)lo;
        s_ylo[tid] = lo;
        s_yhi[tid] = hi;
        s_ywl[tid] = v ? l : 0.0f;                 // validity folded into weights
        s_ywh[tid] = v ? (1.0f - l) : 0.0f;
    } else if (tid >= 64 && tid < 78) {
        int tt = tid - 64;
        int p = tt >> 1, i = tt & 1;
        float xx = x1 + (float)p * bin_w + ((float)i + 0.5f) * bin_w * 0.5f;
        bool v = (xx > -1.0f) && (xx < (float)FEAT_W);
        float x = fmaxf(xx, 0.0f);
        int lo = min((int)floorf(x), FEAT_W - 1);
        int hi = min(lo + 1, FEAT_W - 1);
        if (lo >= FEAT_W - 1) x = (float)lo;
        float l = x - (float)lo;
        s_xlo[tt] = lo;
        s_xhi[tt] = hi;
        s_xwl[tt] = v ? l : 0.0f;
        s_xwh[tt] = v ? (1.0f - l) : 0.0f;
    }
    __syncthreads();

    const int Q = tid >> 4;          // quarter-wave 0..15: cells s = Q + 16k
    const int g = tid & 15;          // channel group: qc + 4g .. qc + 4g+3
    const unsigned short* base = feat + (size_t)b * IMG_USH + qc + 4 * g;

#pragma unroll
    for (int k = 0; k < 4; ++k) {
        const int s = Q + 16 * k;
        if (s < 49) {
            const int ph = (s * 37) >> 8;          // s/7 for s<49
            const int pw = s - ph * 7;
            float ax = 0.f, ay = 0.f, az = 0.f, aw = 0.f;
#pragma unroll
            for (int iy = 0; iy < 2; ++iy) {
                const int ky = ph * 2 + iy;
                const int rl = s_ylo[ky] * FEAT_W;
                const int rh = s_yhi[ky] * FEAT_W;
                const float wyl = s_ywl[ky];
                const float wyh = s_ywh[ky];
#pragma unroll
                for (int ix = 0; ix < 2; ++ix) {
                    const int kx = pw * 2 + ix;
                    const int cl = s_xlo[kx];
                    const int ch = s_xhi[kx];
                    const float w00 = wyh * s_xwh[kx];
                    const float w01 = wyh * s_xwl[kx];
                    const float w10 = wyl * s_xwh[kx];
                    const float w11 = wyl * s_xwl[kx];
                    uint2 t00 = *(const uint2*)(base + (size_t)(rl + cl) * FEAT_C);
                    uint2 t01 = *(const uint2*)(base + (size_t)(rl + ch) * FEAT_C);
                    uint2 t10 = *(const uint2*)(base + (size_t)(rh + cl) * FEAT_C);
                    uint2 t11 = *(const uint2*)(base + (size_t)(rh + ch) * FEAT_C);
                    ax += w00 * __uint_as_float(t00.x << 16) + w01 * __uint_as_float(t01.x << 16)
                        + w10 * __uint_as_float(t10.x << 16) + w11 * __uint_as_float(t11.x << 16);
                    ay += w00 * __uint_as_float(t00.x & 0xffff0000u) + w01 * __uint_as_float(t01.x & 0xffff0000u)
                        + w10 * __uint_as_float(t10.x & 0xffff0000u) + w11 * __uint_as_float(t11.x & 0xffff0000u);
                    az += w00 * __uint_as_float(t00.y << 16) + w01 * __uint_as_float(t01.y << 16)
                        + w10 * __uint_as_float(t10.y << 16) + w11 * __uint_as_float(t11.y << 16);
                    aw += w00 * __uint_as_float(t00.y & 0xffff0000u) + w01 * __uint_as_float(t01.y & 0xffff0000u)
                        + w10 * __uint_as_float(t10.y & 0xffff0000u) + w11 * __uint_as_float(t11.y & 0xffff0000u);
                }
            }
            outbuf[(4 * g + 0) * 49 + s] = ax * 0.25f;
            outbuf[(4 * g + 1) * 49 + s] = ay * 0.25f;
            outbuf[(4 * g + 2) * 49 + s] = az * 0.25f;
            outbuf[(4 * g + 3) * 49 + s] = aw * 0.25f;
        }
    }
    __syncthreads();

    // flat copy: 3136 floats = 784 float4, fully contiguous per block
    const float4* src = (const float4*)outbuf;
    float4* dst = (float4*)(out + (size_t)(roi * FEAT_C + qc) * 49);
    for (int i = tid; i < 784; i += 256) dst[i] = src[i];
}

// ---------- fallback (direct gather, no workspace) ----------
__device__ __forceinline__ float bilinear_tap(const float* __restrict__ plane,
                                              float y, float x) {
    const int H = FEAT_H, W = FEAT_W;
    if (!(y > -1.0f && y < (float)H && x > -1.0f && x < (float)W)) return 0.0f;
    y = fmaxf(y, 0.0f);
    x = fmaxf(x, 0.0f);
    int y0 = min((int)floorf(y), H - 1);
    int x0 = min((int)floorf(x), W - 1);
    int y1 = min(y0 + 1, H - 1);
    int x1 = min(x0 + 1, W - 1);
    if (y0 >= H - 1) y = (float)y0;
    if (x0 >= W - 1) x = (float)x0;
    float ly = y - (float)y0, lx = x - (float)x0;
    float hy = 1.0f - ly, hx = 1.0f - lx;
    return hy * (hx * plane[y0 * W + x0] + lx * plane[y0 * W + x1]) +
           ly * (hx * plane[y1 * W + x0] + lx * plane[y1 * W + x1]);
}

__global__ __launch_bounds__(256) void roialign_direct(
    const float* __restrict__ features, const float* __restrict__ rois,
    float* __restrict__ out, int num_rois) {
    int i = blockIdx.x * blockDim.x + threadIdx.x;
    int total = num_rois * FEAT_C * 49;
    if (i >= total) return;
    int s = i % 49;
    int t = i / 49;
    int c = t % FEAT_C;
    int roi = t / FEAT_C;
    int ph = s / POOLED_W, pw = s % POOLED_W;
    const float* r = rois + roi * 5;
    int b = (int)r[0];
    float x1 = r[1] * SPATIAL_SCALE, y1 = r[2] * SPATIAL_SCALE;
    float x2 = r[3] * SPATIAL_SCALE, y2 = r[4] * SPATIAL_SCALE;
    float bin_w = fmaxf(x2 - x1, 1.0f) * (1.0f / POOLED_W);
    float bin_h = fmaxf(y2 - y1, 1.0f) * (1.0f / POOLED_H);
    const float* plane = features + ((size_t)(b * FEAT_C + c)) * FEAT_S;
    float acc = 0.0f;
#pragma unroll
    for (int iy = 0; iy < 2; ++iy) {
        float yy = y1 + (float)ph * bin_h + ((float)iy + 0.5f) * bin_h * 0.5f;
#pragma unroll
        for (int ix = 0; ix < 2; ++ix) {
            float xx = x1 + (float)pw * bin_w + ((float)ix + 0.5f) * bin_w * 0.5f;
            acc += bilinear_tap(plane, yy, xx);
        }
    }
    out[i] = acc * 0.25f;
}

extern "C" void kernel_launch(void* const* d_in, const int* in_sizes, int n_in,
                              void* d_out, int out_size, void* d_ws, size_t ws_size,
                              hipStream_t stream) {
    const float* features = (const float*)d_in[0];
    const float* rois = (const float*)d_in[1];
    float* out = (float*)d_out;
    int num_rois = in_sizes[1] / 5;
    size_t need = (size_t)FEAT_N * IMG_USH * sizeof(unsigned short);  // ~41 MB
    if (ws_size >= need) {
        unsigned short* nhwc = (unsigned short*)d_ws;
        nchw_to_nhwc_bf16<<<dim3(FEAT_S / ST, FEAT_C / CT, FEAT_N), 256, 0, stream>>>(
            features, nhwc);
        roialign_main<<<num_rois * 4, 256, 0, stream>>>(nhwc, rois, out, num_rois);
    } else {
        int total = num_rois * FEAT_C * 49;
        roialign_direct<<<(total + 255) / 256, 256, 0, stream>>>(features, rois, out,
                                                                 num_rois);
    }
}

// Round 8
// 162.658 us; speedup vs baseline: 1.2617x; 1.2617x over previous
//
#include <hip/hip_runtime.h>

// RoIAlign forward, Detectron-style, sampling_ratio = 2.
// features: [N=2, C=256, H=200, W=200] fp32 ; rois: [1000,5] ; out: [1000,256,7,7]
//
// R8: transpose retiled to 128ch x 64sp so each block writes COMPLETE 256 B
// HBM sectors (128 bf16 = 256 B, naturally aligned) -> the partial-sector
// writeback that tripled R7's WRITE_SIZE (126 MB vs 41 ideal) is structurally
// impossible. Reads are 256 B-aligned 256 B runs; fill keeps R7's register
// batching (8 independent float4 loads in flight before any LDS write).
// Main kernel unchanged (R6-verified).

#define POOLED_H 7
#define POOLED_W 7
#define SPATIAL_SCALE 0.0625f
#define FEAT_N 2
#define FEAT_C 256
#define FEAT_H 200
#define FEAT_W 200
#define FEAT_S (FEAT_H * FEAT_W)               // 40000
#define IMG_USH ((size_t)FEAT_S * FEAT_C)      // ushorts per image in NHWC

// transpose tile: 128 channels x 64 spatial
#define ST 64             // spatial floats per tile (40000/64 = 625 exact)
#define ST4 (ST / 4)      // 16 float4 per channel row
#define CT 128            // channels per tile: 128 bf16 = one full 256 B sector
#define SROW 66           // LDS row stride (ushorts) = 33 dwords (odd -> 4-way max)
#define NF4 (CT * ST4)    // 2048 float4 per block = 8/thread exact
#define NRD (ST * (CT/8)) // 1024 uint4 readouts per block = 4/thread exact

__device__ __forceinline__ unsigned short f2bf(float f) {
    unsigned int u = __float_as_uint(f);
    u += 0x7fffu + ((u >> 16) & 1u);   // round-to-nearest-even
    return (unsigned short)(u >> 16);
}

// ---------- NCHW fp32 -> NHWC bf16 ----------
__global__ __launch_bounds__(256) void nchw_to_nhwc_bf16(
        const float* __restrict__ in, unsigned short* __restrict__ outp) {
    __shared__ unsigned short lds[CT * SROW];   // 16896 B
    const int s0 = blockIdx.x * ST;             // byte offset 256*bx -> 256 B aligned
    const int c0 = blockIdx.y * CT;
    const int b = blockIdx.z;
    const int tid = threadIdx.x;

    // ---- fill: 8 independent float4 loads into registers, then LDS ----
    const float* ibase = in + ((size_t)(b * FEAT_C + c0)) * FEAT_S + s0;
    float4 v[8];
#pragma unroll
    for (int k = 0; k < 8; ++k) {
        int f = tid + 256 * k;          // f < 2048 always
        int c = f >> 4;                 // /16 (power of 2, no div)
        int j = f & 15;
        v[k] = *(const float4*)(ibase + (size_t)c * FEAT_S + 4 * j);
    }
#pragma unroll
    for (int k = 0; k < 8; ++k) {
        int f = tid + 256 * k;
        int c = f >> 4;
        int j = f & 15;
        unsigned int p0 = (unsigned)f2bf(v[k].x) | ((unsigned)f2bf(v[k].y) << 16);
        unsigned int p1 = (unsigned)f2bf(v[k].z) | ((unsigned)f2bf(v[k].w) << 16);
        unsigned short* lp = &lds[c * SROW + 4 * j];
        *(unsigned int*)(lp) = p0;      // two b32 writes (row stride 132 B: uint2
        *(unsigned int*)(lp + 2) = p1;  //  would be 8B-misaligned for odd c)
    }
    __syncthreads();

    // ---- readout: per spatial s, 128 ch x 2 B = one full 256 B sector ----
    // wave: 16 lanes x uint4 = 256 B contiguous store per spatial
    unsigned short* obase = outp + ((size_t)b * FEAT_S + s0) * FEAT_C + c0;
#pragma unroll
    for (int k = 0; k < 4; ++k) {
        int f = tid + 256 * k;          // f < 1024 always
        int s = f >> 4;
        int m = f & 15;                 // uint4 index: channels 8m..8m+7
        const unsigned short* lp = &lds[(8 * m) * SROW + s];
        unsigned int w0 = (unsigned)lp[0] | ((unsigned)lp[SROW] << 16);
        unsigned int w1 = (unsigned)lp[2 * SROW] | ((unsigned)lp[3 * SROW] << 16);
        unsigned int w2 = (unsigned)lp[4 * SROW] | ((unsigned)lp[5 * SROW] << 16);
        unsigned int w3 = (unsigned)lp[6 * SROW] | ((unsigned)lp[7 * SROW] << 16);
        *(uint4*)(obase + (size_t)s * FEAT_C + 8 * m) = make_uint4(w0, w1, w2, w3);
    }
}

// ---------- main: block = (roi, 64-channel quarter) ----------
__global__ __launch_bounds__(256) void roialign_main(
        const unsigned short* __restrict__ feat,   // [N,H,W,C] bf16
        const float* __restrict__ rois,
        float* __restrict__ out,
        int num_rois) {
    __shared__ float outbuf[64 * 49];              // 12544 B
    __shared__ int s_ylo[14], s_yhi[14], s_xlo[14], s_xhi[14];
    __shared__ float s_ywl[14], s_ywh[14], s_xwl[14], s_xwh[14];

    const int bid = blockIdx.x;
    const int roi = bid >> 2;
    const int qc = (bid & 3) * 64;                 // channel quarter base

    const float* r = rois + roi * 5;
    const int b = (int)r[0];
    const float x1 = r[1] * SPATIAL_SCALE;
    const float y1 = r[2] * SPATIAL_SCALE;
    const float x2 = r[3] * SPATIAL_SCALE;
    const float y2 = r[4] * SPATIAL_SCALE;
    const float bin_w = fmaxf(x2 - x1, 1.0f) * (1.0f / POOLED_W);
    const float bin_h = fmaxf(y2 - y1, 1.0f) * (1.0f / POOLED_H);

    const int tid = threadIdx.x;
    if (tid < 14) {
        int p = tid >> 1, i = tid & 1;
        float yy = y1 + (float)p * bin_h + ((float)i + 0.5f) * bin_h * 0.5f;
        bool v = (yy > -1.0f) && (yy < (float)FEAT_H);
        float y = fmaxf(yy, 0.0f);
        int lo = min((int)floorf(y), FEAT_H - 1);
        int hi = min(lo + 1, FEAT_H - 1);
        if (lo >= FEAT_H - 1) y = (float)lo;       // edge snap (reference-exact)
        float l = y - (float)lo;
        s_ylo[tid] = lo;
        s_yhi[tid] = hi;
        s_ywl[tid] = v ? l : 0.0f;                 // validity folded into weights
        s_ywh[tid] = v ? (1.0f - l) : 0.0f;
    } else if (tid >= 64 && tid < 78) {
        int tt = tid - 64;
        int p = tt >> 1, i = tt & 1;
        float xx = x1 + (float)p * bin_w + ((float)i + 0.5f) * bin_w * 0.5f;
        bool v = (xx > -1.0f) && (xx < (float)FEAT_W);
        float x = fmaxf(xx, 0.0f);
        int lo = min((int)floorf(x), FEAT_W - 1);
        int hi = min(lo + 1, FEAT_W - 1);
        if (lo >= FEAT_W - 1) x = (float)lo;
        float l = x - (float)lo;
        s_xlo[tt] = lo;
        s_xhi[tt] = hi;
        s_xwl[tt] = v ? l : 0.0f;
        s_xwh[tt] = v ? (1.0f - l) : 0.0f;
    }
    __syncthreads();

    const int Q = tid >> 4;          // quarter-wave 0..15: cells s = Q + 16k
    const int g = tid & 15;          // channel group: qc + 4g .. qc + 4g+3
    const unsigned short* base = feat + (size_t)b * IMG_USH + qc + 4 * g;

#pragma unroll
    for (int k = 0; k < 4; ++k) {
        const int s = Q + 16 * k;
        if (s < 49) {
            const int ph = (s * 37) >> 8;          // s/7 for s<49
            const int pw = s - ph * 7;
            float ax = 0.f, ay = 0.f, az = 0.f, aw = 0.f;
#pragma unroll
            for (int iy = 0; iy < 2; ++iy) {
                const int ky = ph * 2 + iy;
                const int rl = s_ylo[ky] * FEAT_W;
                const int rh = s_yhi[ky] * FEAT_W;
                const float wyl = s_ywl[ky];
                const float wyh = s_ywh[ky];
#pragma unroll
                for (int ix = 0; ix < 2; ++ix) {
                    const int kx = pw * 2 + ix;
                    const int cl = s_xlo[kx];
                    const int ch = s_xhi[kx];
                    const float w00 = wyh * s_xwh[kx];
                    const float w01 = wyh * s_xwl[kx];
                    const float w10 = wyl * s_xwh[kx];
                    const float w11 = wyl * s_xwl[kx];
                    uint2 t00 = *(const uint2*)(base + (size_t)(rl + cl) * FEAT_C);
                    uint2 t01 = *(const uint2*)(base + (size_t)(rl + ch) * FEAT_C);
                    uint2 t10 = *(const uint2*)(base + (size_t)(rh + cl) * FEAT_C);
                    uint2 t11 = *(const uint2*)(base + (size_t)(rh + ch) * FEAT_C);
                    ax += w00 * __uint_as_float(t00.x << 16) + w01 * __uint_as_float(t01.x << 16)
                        + w10 * __uint_as_float(t10.x << 16) + w11 * __uint_as_float(t11.x << 16);
                    ay += w00 * __uint_as_float(t00.x & 0xffff0000u) + w01 * __uint_as_float(t01.x & 0xffff0000u)
                        + w10 * __uint_as_float(t10.x & 0xffff0000u) + w11 * __uint_as_float(t11.x & 0xffff0000u);
                    az += w00 * __uint_as_float(t00.y << 16) + w01 * __uint_as_float(t01.y << 16)
                        + w10 * __uint_as_float(t10.y << 16) + w11 * __uint_as_float(t11.y << 16);
                    aw += w00 * __uint_as_float(t00.y & 0xffff0000u) + w01 * __uint_as_float(t01.y & 0xffff0000u)
                        + w10 * __uint_as_float(t10.y & 0xffff0000u) + w11 * __uint_as_float(t11.y & 0xffff0000u);
                }
            }
            outbuf[(4 * g + 0) * 49 + s] = ax * 0.25f;
            outbuf[(4 * g + 1) * 49 + s] = ay * 0.25f;
            outbuf[(4 * g + 2) * 49 + s] = az * 0.25f;
            outbuf[(4 * g + 3) * 49 + s] = aw * 0.25f;
        }
    }
    __syncthreads();

    // flat copy: 3136 floats = 784 float4, fully contiguous per block
    const float4* src = (const float4*)outbuf;
    float4* dst = (float4*)(out + (size_t)(roi * FEAT_C + qc) * 49);
    for (int i = tid; i < 784; i += 256) dst[i] = src[i];
}

// ---------- fallback (direct gather, no workspace) ----------
__device__ __forceinline__ float bilinear_tap(const float* __restrict__ plane,
                                              float y, float x) {
    const int H = FEAT_H, W = FEAT_W;
    if (!(y > -1.0f && y < (float)H && x > -1.0f && x < (float)W)) return 0.0f;
    y = fmaxf(y, 0.0f);
    x = fmaxf(x, 0.0f);
    int y0 = min((int)floorf(y), H - 1);
    int x0 = min((int)floorf(x), W - 1);
    int y1 = min(y0 + 1, H - 1);
    int x1 = min(x0 + 1, W - 1);
    if (y0 >= H - 1) y = (float)y0;
    if (x0 >= W - 1) x = (float)x0;
    float ly = y - (float)y0, lx = x - (float)x0;
    float hy = 1.0f - ly, hx = 1.0f - lx;
    return hy * (hx * plane[y0 * W + x0] + lx * plane[y0 * W + x1]) +
           ly * (hx * plane[y1 * W + x0] + lx * plane[y1 * W + x1]);
}

__global__ __launch_bounds__(256) void roialign_direct(
    const float* __restrict__ features, const float* __restrict__ rois,
    float* __restrict__ out, int num_rois) {
    int i = blockIdx.x * blockDim.x + threadIdx.x;
    int total = num_rois * FEAT_C * 49;
    if (i >= total) return;
    int s = i % 49;
    int t = i / 49;
    int c = t % FEAT_C;
    int roi = t / FEAT_C;
    int ph = s / POOLED_W, pw = s % POOLED_W;
    const float* r = rois + roi * 5;
    int b = (int)r[0];
    float x1 = r[1] * SPATIAL_SCALE, y1 = r[2] * SPATIAL_SCALE;
    float x2 = r[3] * SPATIAL_SCALE, y2 = r[4] * SPATIAL_SCALE;
    float bin_w = fmaxf(x2 - x1, 1.0f) * (1.0f / POOLED_W);
    float bin_h = fmaxf(y2 - y1, 1.0f) * (1.0f / POOLED_H);
    const float* plane = features + ((size_t)(b * FEAT_C + c)) * FEAT_S;
    float acc = 0.0f;
#pragma unroll
    for (int iy = 0; iy < 2; ++iy) {
        float yy = y1 + (float)ph * bin_h + ((float)iy + 0.5f) * bin_h * 0.5f;
#pragma unroll
        for (int ix = 0; ix < 2; ++ix) {
            float xx = x1 + (float)pw * bin_w + ((float)ix + 0.5f) * bin_w * 0.5f;
            acc += bilinear_tap(plane, yy, xx);
        }
    }
    out[i] = acc * 0.25f;
}

extern "C" void kernel_launch(void* const* d_in, const int* in_sizes, int n_in,
                              void* d_out, int out_size, void* d_ws, size_t ws_size,
                              hipStream_t stream) {
    const float* features = (const float*)d_in[0];
    const float* rois = (const float*)d_in[1];
    float* out = (float*)d_out;
    int num_rois = in_sizes[1] / 5;
    size_t need = (size_t)FEAT_N * IMG_USH * sizeof(unsigned short);  // ~41 MB
    if (ws_size >= need) {
        unsigned short* nhwc = (unsigned short*)d_ws;
        nchw_to_nhwc_bf16<<<dim3(FEAT_S / ST, FEAT_C / CT, FEAT_N), 256, 0, stream>>>(
            features, nhwc);
        roialign_main<<<num_rois * 4, 256, 0, stream>>>(nhwc, rois, out, num_rois);
    } else {
        int total = num_rois * FEAT_C * 49;
        roialign_direct<<<(total + 255) / 256, 256, 0, stream>>>(features, rois, out,
                                                                 num_rois);
    }
}